// Round 6
// baseline (308.162 us; speedup 1.0000x reference)
//
#include <hip/hip_runtime.h>
#include <hip/hip_fp16.h>

// Guided filter fused kernel, round 9b: 3 blocks/CU, dual-ring, 2-phase
// pipeline.  (16,3,512,512) fp32, r=8 (17x17 box, zero 'same' pad, analytic N).
// Identical to round 9 except the unaligned float4 global loads now go
// through __builtin_memcpy (guaranteed-defined 4B-aligned 16B loads; clang
// emits global_load_dwordx4).  r9 bench was an infra failure, not a verdict.
//
// Structure (448 threads = 7 waves, KCH=4 stacked 32x32 tiles):
//   RING: H-sums (sI,sp,sIp,sII) float4 [48 slots][48 cols], slot = t mod 48,
//         phys col = hc ^ (slot&7) (slot&7 == t&7 since 48 = 0 mod 8). 36864 B.
//   ABR : a,b as __half2, ring slot = ay mod 48, stride 51.  9792 B.
//   HABR: horizontal 17-sums of a,b, __half2 [48][33].  6336 B.
//   Total 52992 B -> 3 blocks/CU.  Three disjoint arrays, no overlays; every
//   ring-slot overwrite is barrier-separated from its last reader (traced for
//   all t in [0,160), ay in [0,144)).
// fp16 error budget: |a|<~2.5, |b|<~3.5, HAB ~ O(40) -> added q error
// ~1.5e-3 against threshold 1.21e-2 (fp32 version measured 3.9e-3).
//
// Staging stage deleted: s2 reads I,p directly from global (rows L1/L2
// resident; HBM at 14% of peak).  Interior path: 6 4B-aligned 16B loads per
// image per thread; max col touched = x0+65 <= 497 for interior blocks.
//
// Main loop, 2 barriers per group (role-split waves):
//   phase A: s4(i) [tid<192: AB->HAB]  ||  s2f(t 32i+64..+32) [tid>=192;
//            target slots' last reader was s3 of iter i-1, barrier-separated]
//   bar
//   phase B: s3(ay 32i+48..+32) [tid<192; writes AB slots whose last reader
//            was s4(i) in phase A]  ||  s5(i) [tid>=192: HAB->q]
//   bar

#define RAD  8
#define H    512
#define W    512
#define TILE 32
#define KCH  4
#define EPS  0.01f

__global__ __launch_bounds__(448, 6)
void guided_filter_kernel(const float* __restrict__ Ig,
                          const float* __restrict__ Pg,
                          float* __restrict__ out)
{
    __shared__ __align__(16) float4  RING[48 * 48];   // 36864 B
    __shared__ __align__(8)  __half2 ABR[48 * 51];    //  9792 B
    __shared__ __align__(8)  __half2 HABR[48 * 33];   //  6336 B

    const int tid   = threadIdx.x;
    const int plane = blockIdx.z;
    const int x0 = blockIdx.x * TILE - 2 * RAD;
    const int Y0 = blockIdx.y * (TILE * KCH);
    const float* Ib = Ig + (size_t)plane * (H * W);
    const float* Pb = Pg + (size_t)plane * (H * W);
    float* Ob = out + (size_t)plane * (H * W);

    // ---- s2f: horizontal 17-sums straight from global -> RING rows ----
    // tid2 in [0, nrows*8): r = tid2>>3, e = tid2&7; H cols [6e, 6e+6).
    // Raw window cols [6e, 6e+22]; loads cover [6e, 6e+24).
    auto s2f = [&](int T0, int nrows, int tid2) {
        if (tid2 < nrows * 8) {
            const int r = tid2 >> 3, e = tid2 & 7;
            int slot = (T0 % 48) + r; if (slot >= 48) slot -= 48;
            const int rl = r & 7;               // == slot & 7 (T0%48 == 0 mod 8)
            const int ty = Y0 + T0 - 16 + r;
            const int cb = 6 * e;
            float4 bI[6], bP[6];
            const bool xint = (x0 >= 0) && (x0 + 64 <= W);
            if (xint && ((unsigned)ty < (unsigned)H)) {
                const float* pi = Ib + ty * W + x0 + cb;
                const float* pp = Pb + ty * W + x0 + cb;
                #pragma unroll
                for (int k = 0; k < 6; ++k) {
                    __builtin_memcpy(&bI[k], pi + 4 * k, 16);
                    __builtin_memcpy(&bP[k], pp + 4 * k, 16);
                }
            } else {
                const bool vy = (unsigned)ty < (unsigned)H;
                float* fI = (float*)bI;
                float* fP = (float*)bP;
                #pragma unroll
                for (int c = 0; c < 24; ++c) {
                    int gx = x0 + cb + c;
                    bool v = vy && ((unsigned)gx < (unsigned)W);
                    fI[c] = v ? Ib[ty * W + gx] : 0.f;
                    fP[c] = v ? Pb[ty * W + gx] : 0.f;
                }
            }
            const float* fI = (const float*)bI;
            const float* fP = (const float*)bP;
            float4 S = make_float4(0.f, 0.f, 0.f, 0.f);
            #pragma unroll
            for (int c = 0; c <= 16; ++c) {
                float iv = fI[c], pv = fP[c];
                S.x += iv; S.y += pv; S.z += iv * pv; S.w += iv * iv;
            }
            float4* Hrow = &RING[slot * 48];
            #pragma unroll
            for (int k = 0; k < 6; ++k) {
                Hrow[(cb + k) ^ rl] = S;
                if (k < 5) {
                    float ia = fI[17 + k], pa = fP[17 + k];
                    float is = fI[k],      ps = fP[k];
                    S.x += ia - is;
                    S.y += pa - ps;
                    S.z += ia * pa - is * ps;
                    S.w += ia * ia - is * is;
                }
            }
        }
    };

    // ---- s3: vertical 17-sums over RING -> a,b (fp16) -> ABR ----
    // tid < 48*nch: col = tid%48, chunk rows ay0 = AY + 8*(tid/48).
    // base = ay0 mod 48 is 8-aligned -> slot&7 == j&7 compile-time; single
    // ring wrap at j >= tW via cndmask between alo/ahi twins.
    auto s3 = [&](int AY, int nch) {
        if (tid < 48 * nch) {
            const int col = tid % 48;
            const int ay0 = AY + 8 * (tid / 48);
            const int base = ay0 % 48;
            const int tW = 48 - base;
            const char* Rb = (const char*)RING;
            unsigned alo[8], ahi[8];
            #pragma unroll
            for (int k = 0; k < 8; ++k) {
                alo[k] = (unsigned)(base * 768 + ((col ^ k) << 4));
                ahi[k] = alo[k] - 36864u;
            }
            float4 S = make_float4(0.f, 0.f, 0.f, 0.f);
            #pragma unroll
            for (int j = 0; j < 17; ++j) {
                unsigned off = (j >= tW ? ahi[j & 7] : alo[j & 7])
                               + (unsigned)(j * 768);
                float4 v = *(const float4*)(Rb + off);
                S.x += v.x; S.y += v.y; S.z += v.z; S.w += v.w;
            }
            const int gx = x0 + RAD + col;
            const int nx = min(gx + RAD, W - 1) - max(gx - RAD, 0) + 1;
            #pragma unroll
            for (int kk = 0; kk < 8; ++kk) {
                int ya = Y0 + ay0 + kk - 8;       // image row of this a,b row
                float a = 0.f, b = 0.f;
                if (((unsigned)ya < (unsigned)H) && ((unsigned)gx < (unsigned)W)) {
                    int ny = min(ya + RAD, H - 1) - max(ya - RAD, 0) + 1;
                    float invN = __builtin_amdgcn_rcpf((float)(nx * ny));
                    float mI = S.x * invN, mp = S.y * invN;
                    float cov = S.z * invN - mI * mp;
                    float var = S.w * invN - mI * mI;
                    a = cov * __builtin_amdgcn_rcpf(var + EPS);
                    b = mp - a * mI;
                }
                ABR[(base + kk) * 51 + col] = __floats2half2_rn(a, b);
                if (kk < 7) {
                    unsigned offs = (kk >= tW ? ahi[kk & 7] : alo[kk & 7])
                                    + (unsigned)(kk * 768);
                    int ja = kk + 17;
                    unsigned offa = (ja >= tW ? ahi[ja & 7] : alo[ja & 7])
                                    + (unsigned)(ja * 768);
                    float4 va = *(const float4*)(Rb + offa);
                    float4 vs = *(const float4*)(Rb + offs);
                    S.x += va.x - vs.x; S.y += va.y - vs.y;
                    S.z += va.z - vs.z; S.w += va.w - vs.w;
                }
            }
        }
    };

    // ---- s4: horizontal 17-sums of a,b -> HABR (group i) ----
    // tid < 192: r = tid%48 (ab row, ay = 32i + r), e = tid/48, cols [8e,8e+8).
    auto s4 = [&](int i) {
        if (tid < 192) {
            const int r = tid % 48, e = tid / 48;
            const int c0 = 8 * e;
            int slot = (32 * i) % 48 + r; if (slot >= 48) slot -= 48;
            const __half2* Arow = &ABR[slot * 51];
            float2 S = make_float2(0.f, 0.f);
            #pragma unroll
            for (int d = 0; d <= 16; ++d) {
                float2 v = __half22float2(Arow[c0 + d]);
                S.x += v.x; S.y += v.y;
            }
            #pragma unroll
            for (int k = 0; k < 8; ++k) {
                HABR[r * 33 + c0 + k] = __floats2half2_rn(S.x, S.y);
                if (k < 7) {
                    float2 va = __half22float2(Arow[c0 + k + 17]);
                    float2 vs = __half22float2(Arow[c0 + k]);
                    S.x += va.x - vs.x; S.y += va.y - vs.y;
                }
            }
        }
    };

    // ---- s5: vertical 17-sums of HABR -> q (group i) ----
    // tid in [192,448): qc = t2&31, 8 chunks x 4 rows.
    auto s5 = [&](int i) {
        if (tid >= 192) {
            const int t2 = tid - 192;
            const int qc = t2 & 31, oy0 = (t2 >> 5) * 4;
            float2 S = make_float2(0.f, 0.f);
            #pragma unroll
            for (int j = 0; j < 17; ++j) {
                float2 v = __half22float2(HABR[(oy0 + j) * 33 + qc]);
                S.x += v.x; S.y += v.y;
            }
            const int gx = x0 + 2 * RAD + qc;
            const int nx = min(gx + RAD, W - 1) - max(gx - RAD, 0) + 1;
            #pragma unroll
            for (int k = 0; k < 4; ++k) {
                int gy = Y0 + 32 * i + oy0 + k;
                int ny = min(gy + RAD, H - 1) - max(gy - RAD, 0) + 1;
                float invN = __builtin_amdgcn_rcpf((float)(nx * ny));
                float iv = Ib[gy * W + gx];
                Ob[gy * W + gx] = S.x * invN * iv + S.y * invN;
                if (k < 3) {
                    float2 va = __half22float2(HABR[(oy0 + k + 17) * 33 + qc]);
                    float2 vs = __half22float2(HABR[(oy0 + k) * 33 + qc]);
                    S.x += va.x - vs.x; S.y += va.y - vs.y;
                }
            }
        }
    };

    // ---- Prologue: ring t[0,48), a,b ay[0,48) ----
    s2f(0, 48, tid);                  // slots 0..47 = t 0..47
    __syncthreads();
    s3(0, 4);                         // ay 0..31  (needs t 0..47)
    __syncthreads();
    s2f(48, 16, tid);                 // t 48..63 -> slots 0..15 (t 0..15 dead)
    __syncthreads();
    s3(32, 2);                        // ay 32..47 (needs t 32..63)
    __syncthreads();

    // ---- Main loop: 2 barriers per group ----
    #pragma unroll 1
    for (int i = 0; i < KCH; ++i) {
        // phase A
        if (tid < 192) s4(i);
        else if (i < KCH - 1) s2f(32 * i + 64, 32, tid - 192);
        __syncthreads();
        // phase B
        if (tid < 192) { if (i < KCH - 1) s3(32 * i + 48, 4); }
        else s5(i);
        __syncthreads();
    }
}

extern "C" void kernel_launch(void* const* d_in, const int* in_sizes, int n_in,
                              void* d_out, int out_size, void* d_ws, size_t ws_size,
                              hipStream_t stream) {
    const float* I = (const float*)d_in[0];
    const float* P = (const float*)d_in[1];
    float* out = (float*)d_out;
    int planes = in_sizes[0] / (H * W);   // 48
    dim3 grid(W / TILE, H / (TILE * KCH), planes);
    guided_filter_kernel<<<grid, dim3(448), 0, stream>>>(I, P, out);
}

// Round 8
// 262.147 us; speedup vs baseline: 1.1755x; 1.1755x over previous
//
#include <hip/hip_runtime.h>

// Guided filter fused kernel, round 10b: r5 base (best measured, 155 us) +
// T14 async-STAGE split on the in-loop staging.  (r10 had a stray editing
// artifact that broke compilation; this is the corrected resubmit.)
// (16,3,512,512) fp32, r=8 (17x17 box, zero 'same' padding, analytic N).
//
// Per block: FOUR vertically stacked 32x32 output tiles (128 output rows).
// H (horizontal 17-sums of I,p,Ip,II) lives in a 64-row RING; group 0 stages
// 64 raw rows, groups 1..3 stage only 32 NEW rows.
//
// T14 split (the one change vs r5): the 32-row tail staging used to issue
// global loads AND ds_write them between s4's barrier and s5 -> full HBM
// latency exposed in-phase.  Now: loads issue at the TOP of the group body
// (8 VGPRs held across s3+s4, thousands of cycles of cover); the swizzle +
// ds_write runs at the old call site.  Hazard window unchanged: writes to
// F4 bytes [0,16384) happen after s4's barrier (AB reads done), disjoint
// from s5's HAB reads (bytes 19200..31872).
//
// LDS = exactly 80 KiB -> 2 blocks/CU:
//   F4 : region (I,p) as float4 granules [64 rows][32 granules], swizzled
//        phys_granule = g ^ (row&7), halves swapped iff (row&1). 32768 B.
//        After stage 2, same space holds AB (48 x stride 50 float2) and
//        HAB (48 x stride 33 float2).  Tail staging reuses bytes [0,16384).
//   H4 : (sI,sp,sIp,sII) float4 ring [64][48], phys_col = col ^ (row&7).
// Ring slot = row&63; slot&7 == row&7 because group offsets are mult. of 32.

#define RAD  8
#define H    512
#define W    512
#define TILE 32
#define KCH  4
#define EPS  0.01f

__global__ __launch_bounds__(512, 4)
void guided_filter_kernel(const float* __restrict__ Ig,
                          const float* __restrict__ Pg,
                          float* __restrict__ out)
{
    __shared__ __align__(16) float4 F4[64 * 32];   // 32768 B
    __shared__ __align__(16) float4 H4[64 * 48];   // 49152 B (ring)

    float2* F2p = (float2*)F4;
    float2* AB  = (float2*)F4;                 // 48 rows x stride 50 (19200 B)
    float2* HAB = (float2*)F4 + 48 * 50;       // 48 rows x stride 33 (12672 B)

    const int tid   = threadIdx.x;
    const int plane = blockIdx.z;
    const int x0 = blockIdx.x * TILE - 2 * RAD;
    const int Y0 = blockIdx.y * (TILE * KCH);
    const float* Ib = Ig + (size_t)plane * (H * W);
    const float* Pb = Pg + (size_t)plane * (H * W);
    float* Ob = out + (size_t)plane * (H * W);

    // ---- Stage 1 (prologue form): raw rows [ybase, ybase+64) -> F4 ----
    auto stage_raw64 = [&](int ybase) {
        const bool interior = (x0 >= 0) && (ybase >= 0) &&
                              (x0 + 64 <= W) && (ybase + 64 <= H);
        if (interior) {
            #pragma unroll
            for (int it = 0; it < 2; ++it) {
                int idx = it * 512 + tid;
                int ry = idx >> 4, f4 = idx & 15;
                int rl = ry & 7, pf = ry & 1;
                const float* ip = Ib + (ybase + ry) * W + x0 + 4 * f4;
                const float* pp = Pb + (ybase + ry) * W + x0 + 4 * f4;
                float4 iv = *(const float4*)ip;
                float4 pv = *(const float4*)pp;
                float2 e0 = make_float2(iv.x, pv.x), e1 = make_float2(iv.y, pv.y);
                float2 e2 = make_float2(iv.z, pv.z), e3 = make_float2(iv.w, pv.w);
                float2 a0 = pf ? e1 : e0, a1 = pf ? e0 : e1;
                float2 b0 = pf ? e3 : e2, b1 = pf ? e2 : e3;
                float4* Fr = &F4[ry * 32];
                Fr[(2 * f4) ^ rl]     = make_float4(a0.x, a0.y, a1.x, a1.y);
                Fr[(2 * f4 + 1) ^ rl] = make_float4(b0.x, b0.y, b1.x, b1.y);
            }
        } else {
            #pragma unroll
            for (int it = 0; it < 2; ++it) {
                int idx = it * 512 + tid;
                int ry = idx >> 4, f4 = idx & 15;
                int rl = ry & 7, pf = ry & 1;
                int gy = ybase + ry;
                float2 el[4];
                #pragma unroll
                for (int k = 0; k < 4; ++k) {
                    int gx = x0 + 4 * f4 + k;
                    bool v = ((unsigned)gy < (unsigned)H) && ((unsigned)gx < (unsigned)W);
                    el[k].x = v ? Ib[gy * W + gx] : 0.f;
                    el[k].y = v ? Pb[gy * W + gx] : 0.f;
                }
                float2 a0 = pf ? el[1] : el[0], a1 = pf ? el[0] : el[1];
                float2 b0 = pf ? el[3] : el[2], b1 = pf ? el[2] : el[3];
                float4* Fr = &F4[ry * 32];
                Fr[(2 * f4) ^ rl]     = make_float4(a0.x, a0.y, a1.x, a1.y);
                Fr[(2 * f4 + 1) ^ rl] = make_float4(b0.x, b0.y, b1.x, b1.y);
            }
        }
    };

    // ---- T14 split staging for the 32-row tails (1 granule/thread) ----
    // load: issue global loads into regs (no LDS access -> placeable anywhere)
    auto stage_load = [&](int ybase, float4& iv, float4& pv) {
        const int ry = tid >> 4, f4 = tid & 15;
        const int gy = ybase + ry;
        const bool interior = (x0 >= 0) && (x0 + 64 <= W) &&
                              (ybase >= 0) && (ybase + 32 <= H);
        if (interior) {
            iv = *(const float4*)(Ib + gy * W + x0 + 4 * f4);
            pv = *(const float4*)(Pb + gy * W + x0 + 4 * f4);
        } else {
            float* fi = (float*)&iv;
            float* fp = (float*)&pv;
            #pragma unroll
            for (int k = 0; k < 4; ++k) {
                int gx = x0 + 4 * f4 + k;
                bool v = ((unsigned)gy < (unsigned)H) && ((unsigned)gx < (unsigned)W);
                fi[k] = v ? Ib[gy * W + gx] : 0.f;
                fp[k] = v ? Pb[gy * W + gx] : 0.f;
            }
        }
    };
    // write: swizzle + ds_write (loads have had s3+s4 to land)
    auto stage_write = [&](float4 iv, float4 pv) {
        const int ry = tid >> 4, f4 = tid & 15;
        const int rl = ry & 7, pf = ry & 1;
        float2 e0 = make_float2(iv.x, pv.x), e1 = make_float2(iv.y, pv.y);
        float2 e2 = make_float2(iv.z, pv.z), e3 = make_float2(iv.w, pv.w);
        float2 a0 = pf ? e1 : e0, a1 = pf ? e0 : e1;
        float2 b0 = pf ? e3 : e2, b1 = pf ? e2 : e3;
        float4* Fr = &F4[ry * 32];
        Fr[(2 * f4) ^ rl]     = make_float4(a0.x, a0.y, a1.x, a1.y);
        Fr[(2 * f4 + 1) ^ rl] = make_float4(b0.x, b0.y, b1.x, b1.y);
    };

    // ---- Stage 2: horizontal 17-sums of staged rows -> H ring ----
    auto s2_rows = [&](int tbase, bool full) {
        if (full || tid < 256) {
            const int r  = tid >> 3, e = tid & 7;
            const int rl = r & 7, pf = r & 1;
            const int c0 = 6 * e;
            const float4* Fr = &F4[r * 32];
            const float2* Er = &F2p[r * 64];
            float4 S = make_float4(0.f, 0.f, 0.f, 0.f);
            const int gb = 3 * e;
            #pragma unroll
            for (int m = 0; m < 8; ++m) {   // elements c0 .. c0+15
                float4 fr = Fr[(gb + m) ^ rl];
                S.x += fr.x + fr.z;
                S.y += fr.y + fr.w;
                S.z += fr.x * fr.y + fr.z * fr.w;
                S.w += fr.x * fr.x + fr.z * fr.z;
            }
            {
                int c = c0 + 16;            // even -> within-granule slot = pf
                float2 v = Er[(((c >> 1) ^ rl) << 1) | pf];
                S.x += v.x; S.y += v.y; S.z += v.x * v.y; S.w += v.x * v.x;
            }
            const int slot = (tbase + r) & 63;   // slot&7 == r&7 (tbase % 32 == 0)
            float4* Hrow = &H4[slot * 48];
            #pragma unroll
            for (int k = 0; k < 6; ++k) {
                Hrow[(c0 + k) ^ rl] = S;
                if (k < 5) {
                    int ca = c0 + k + 17, cs = c0 + k;
                    float2 va = Er[(((ca >> 1) ^ rl) << 1) | ((ca & 1) ^ pf)];
                    float2 vs = Er[(((cs >> 1) ^ rl) << 1) | ((cs & 1) ^ pf)];
                    S.x += va.x - vs.x;
                    S.y += va.y - vs.y;
                    S.z += va.x * va.y - vs.x * vs.y;
                    S.w += va.x * va.x - vs.x * vs.x;
                }
            }
        }
    };

    // ---- Stage 3: vertical 17-sums over H ring rows [32g, 32g+48) -> a,b ----
    auto s3g = [&](int g) {
        if (tid < 384) {
            const int col = tid % 48, chunk = tid / 48;
            const int cy0 = chunk * 6;
            const int tb = 32 * g;
            float4 S = make_float4(0.f, 0.f, 0.f, 0.f);
            #pragma unroll
            for (int j = 0; j < 17; ++j) {
                int row = tb + cy0 + j;
                float4 v = H4[(row & 63) * 48 + (col ^ (row & 7))];
                S.x += v.x; S.y += v.y; S.z += v.z; S.w += v.w;
            }
            int gx = x0 + RAD + col;
            int nx = min(gx + RAD, W - 1) - max(gx - RAD, 0) + 1;
            #pragma unroll
            for (int k = 0; k < 6; ++k) {
                int cy = cy0 + k;
                int gy = Y0 + 32 * g - RAD + cy;
                float a = 0.f, b = 0.f;
                if (((unsigned)gy < (unsigned)H) && ((unsigned)gx < (unsigned)W)) {
                    int ny = min(gy + RAD, H - 1) - max(gy - RAD, 0) + 1;
                    float invN = __builtin_amdgcn_rcpf((float)(nx * ny));
                    float mI = S.x * invN, mp = S.y * invN;
                    float cov = S.z * invN - mI * mp;
                    float var = S.w * invN - mI * mI;
                    a = cov * __builtin_amdgcn_rcpf(var + EPS);
                    b = mp - a * mI;
                }
                AB[cy * 50 + col] = make_float2(a, b);
                if (k < 5) {
                    int ra = tb + cy + 17, rs = tb + cy;
                    float4 va = H4[(ra & 63) * 48 + (col ^ (ra & 7))];
                    float4 vs = H4[(rs & 63) * 48 + (col ^ (rs & 7))];
                    S.x += va.x - vs.x; S.y += va.y - vs.y;
                    S.z += va.z - vs.z; S.w += va.w - vs.w;
                }
            }
        }
    };

    // ---- Stage 4: horizontal 17-sums of a,b -> HAB ----
    auto s4 = [&]() {
        if (tid < 384) {
            const int r = tid % 48, e = tid / 48;   // e in 0..7, 4 output cols each
            const int c0 = 4 * e;
            const float2* row  = &AB[r * 50];
            const float4* rowg = (const float4*)row;   // rows 16B-aligned
            float2 S = make_float2(0.f, 0.f);
            #pragma unroll
            for (int m = 0; m < 8; ++m) {           // elements c0 .. c0+15
                float4 gq = rowg[2 * e + m];
                S.x += gq.x + gq.z;
                S.y += gq.y + gq.w;
            }
            {
                float2 v = row[c0 + 16];
                S.x += v.x; S.y += v.y;
            }
            #pragma unroll
            for (int k = 0; k < 4; ++k) {
                HAB[r * 33 + c0 + k] = S;
                if (k < 3) {
                    float2 va = row[c0 + k + 17];
                    float2 vs = row[c0 + k];
                    S.x += va.x - vs.x; S.y += va.y - vs.y;
                }
            }
        }
    };

    // ---- Stage 5: vertical 17-sums of HAB -> q ----
    auto s5g = [&](int g) {
        const int col = tid & 31, chunk = tid >> 5;   // 16 chunks x 2 rows
        const int oy0 = chunk * 2;
        float2 S = make_float2(0.f, 0.f);
        #pragma unroll
        for (int j = 0; j < 17; ++j) {
            float2 v = HAB[(oy0 + j) * 33 + col];
            S.x += v.x; S.y += v.y;
        }
        int gx = x0 + 2 * RAD + col;
        int nx = min(gx + RAD, W - 1) - max(gx - RAD, 0) + 1;
        #pragma unroll
        for (int k = 0; k < 2; ++k) {
            int oy = oy0 + k;
            int gy = Y0 + 32 * g + oy;
            int ny = min(gy + RAD, H - 1) - max(gy - RAD, 0) + 1;
            float invN = __builtin_amdgcn_rcpf((float)(nx * ny));
            float iv = Ib[gy * W + gx];
            Ob[gy * W + gx] = S.x * invN * iv + S.y * invN;
            if (k < 1) {
                float2 va = HAB[(oy + 17) * 33 + col];
                float2 vs = HAB[oy * 33 + col];
                S.x += va.x - vs.x; S.y += va.y - vs.y;
            }
        }
    };

    // ---- Chained schedule ----
    stage_raw64(Y0 - 2 * RAD);            // raw rows t in [0,64)
    __syncthreads();
    s2_rows(0, true);                     // H ring slots 0..63
    float4 siv, spv;                      // T14 in-flight staging regs
    #pragma unroll 1
    for (int g = 0; g < KCH; ++g) {
        if (g < KCH - 1)
            stage_load(Y0 + 32 * g + 48, siv, spv);  // issue loads EARLY
        __syncthreads();
        s3g(g);                           // H ring -> AB (in F4 space)
        __syncthreads();
        s4();                             // AB -> HAB
        __syncthreads();
        if (g < KCH - 1)
            stage_write(siv, spv);        // ds_write (loads long landed)
        s5g(g);                           // HAB -> out (overlaps LDS writes)
        if (g < KCH - 1) {
            __syncthreads();
            s2_rows(32 * g + 64, false);  // append 32 H rows to ring
        }
    }
}

extern "C" void kernel_launch(void* const* d_in, const int* in_sizes, int n_in,
                              void* d_out, int out_size, void* d_ws, size_t ws_size,
                              hipStream_t stream) {
    const float* I = (const float*)d_in[0];
    const float* P = (const float*)d_in[1];
    float* out = (float*)d_out;
    int planes = in_sizes[0] / (H * W);   // 48
    dim3 grid(W / TILE, H / (TILE * KCH), planes);
    guided_filter_kernel<<<grid, dim3(512), 0, stream>>>(I, P, out);
}